// Round 4
// baseline (331.414 us; speedup 1.0000x reference)
//
#include <hip/hip_runtime.h>
#include <math.h>

#define N_NODES 100000
#define N_EDGES 1600000
#define D_IN 256
#define N_HEADS 4
#define D_OUT 32
#define D_HID 128   // N_HEADS*D_OUT
#define NEG_SLOPE 0.2f

// bucketed sort params
#define BUCKET_SHIFT 8
#define BUCKET_NODES 256
#define NB ((N_NODES + BUCKET_NODES - 1) / BUCKET_NODES)  // 391
#define CAP 6144      // >> mean 4096 + 32 sigma
#define TILE 2048
#define EPT 8         // edges per thread in k_bucket
#define N_TILES ((N_EDGES + TILE - 1) / TILE)             // 782

typedef __attribute__((ext_vector_type(8))) short bf16x8;
typedef __attribute__((ext_vector_type(4))) float f32x4;

// hardware packed f32->bf16 (RNE), 1 inst per 2 elements
static __device__ __forceinline__ unsigned cvt2(float lo, float hi) {
  unsigned r;
  asm("v_cvt_pk_bf16_f32 %0, %1, %2" : "=v"(r) : "v"(lo), "v"(hi));
  return r;
}
static __device__ __forceinline__ float bfu_lo(unsigned u) {
  union { unsigned u; float f; } c; c.u = u << 16; return c.f;
}
static __device__ __forceinline__ float bfu_hi(unsigned u) {
  union { unsigned u; float f; } c; c.u = u & 0xFFFF0000u; return c.f;
}

// ---------------- GEMM: ftb[N,128](bf16) = x[N,256] @ w[128,256]^T ----------
// Fused epilogue also emits el[n,h] = <ft[n,h,:], al[h,:]>, er likewise,
// computed from the f32 accumulators (more accurate than re-reading bf16).
#define LDA 40  // padded LDS row stride in bf16 elems
__global__ __launch_bounds__(256) void k_gemm(const float* __restrict__ x,
                                              const float* __restrict__ w,
                                              const float* __restrict__ al,
                                              const float* __restrict__ ar,
                                              unsigned short* __restrict__ ftb,
                                              float* __restrict__ el,
                                              float* __restrict__ er) {
  __shared__ short As[128 * LDA];
  __shared__ short Bs[128 * LDA];
  int t = threadIdx.x;
  int wave = t >> 6, lane = t & 63;
  int quad = lane >> 4, l16 = lane & 15;
  int rowBase = blockIdx.x * 128;
  int wm = (wave >> 1) * 64, wn = (wave & 1) * 64;
  f32x4 acc[4][4];
  #pragma unroll
  for (int mt = 0; mt < 4; ++mt)
    #pragma unroll
    for (int nt = 0; nt < 4; ++nt) {
      acc[mt][nt][0] = 0.f; acc[mt][nt][1] = 0.f;
      acc[mt][nt][2] = 0.f; acc[mt][nt][3] = 0.f;
    }

  for (int kb = 0; kb < D_IN; kb += 32) {
    #pragma unroll
    for (int p = 0; p < 4; ++p) {
      int idx = p * 256 + t;
      int r = idx >> 3;
      int kq = (idx & 7) * 4;
      int row = rowBase + r;
      float4 v = make_float4(0.f, 0.f, 0.f, 0.f);
      if (row < N_NODES) v = *(const float4*)&x[(size_t)row * D_IN + kb + kq];
      unsigned* d = (unsigned*)&As[r * LDA + kq];
      d[0] = cvt2(v.x, v.y);
      d[1] = cvt2(v.z, v.w);
    }
    #pragma unroll
    for (int p = 0; p < 4; ++p) {
      int idx = p * 256 + t;
      int r = idx >> 3;
      int kq = (idx & 7) * 4;
      float4 v = *(const float4*)&w[(size_t)r * D_IN + kb + kq];
      unsigned* d = (unsigned*)&Bs[r * LDA + kq];
      d[0] = cvt2(v.x, v.y);
      d[1] = cvt2(v.z, v.w);
    }
    __syncthreads();
    bf16x8 af[4], bfr[4];
    #pragma unroll
    for (int mt = 0; mt < 4; ++mt)
      af[mt] = *(const bf16x8*)&As[(wm + mt * 16 + l16) * LDA + quad * 8];
    #pragma unroll
    for (int nt = 0; nt < 4; ++nt)
      bfr[nt] = *(const bf16x8*)&Bs[(wn + nt * 16 + l16) * LDA + quad * 8];
    #pragma unroll
    for (int mt = 0; mt < 4; ++mt)
      #pragma unroll
      for (int nt = 0; nt < 4; ++nt)
        acc[mt][nt] = __builtin_amdgcn_mfma_f32_16x16x32_bf16(af[mt], bfr[nt], acc[mt][nt], 0, 0, 0);
    __syncthreads();
  }

  // ftb store
  #pragma unroll
  for (int mt = 0; mt < 4; ++mt) {
    #pragma unroll
    for (int nt = 0; nt < 4; ++nt) {
      int col = wn + nt * 16 + l16;
      #pragma unroll
      for (int r = 0; r < 4; r += 2) {
        unsigned p = cvt2(acc[mt][nt][r], acc[mt][nt][r + 1]);
        int row = rowBase + wm + mt * 16 + quad * 4 + r;
        if (row < N_NODES)
          ftb[(size_t)row * D_HID + col] = (unsigned short)p;
        if (row + 1 < N_NODES)
          ftb[(size_t)(row + 1) * D_HID + col] = (unsigned short)(p >> 16);
      }
    }
  }

  // fused el/er: lane's 4 cols are wn+nt*16+l16; heads (h0,h0) for nt=0,1 and
  // (h0+1,h0+1) for nt=2,3 where h0 = wn>>5. Reduce over l16 within the quad.
  float alf[4], arf[4];
  #pragma unroll
  for (int q = 0; q < 4; ++q) {
    alf[q] = al[wn + q * 16 + l16];
    arf[q] = ar[wn + q * 16 + l16];
  }
  int h0 = wn >> 5;
  #pragma unroll
  for (int mt = 0; mt < 4; ++mt) {
    #pragma unroll
    for (int r = 0; r < 4; ++r) {
      float sl0 = acc[mt][0][r] * alf[0] + acc[mt][1][r] * alf[1];
      float sl1 = acc[mt][2][r] * alf[2] + acc[mt][3][r] * alf[3];
      float sr0 = acc[mt][0][r] * arf[0] + acc[mt][1][r] * arf[1];
      float sr1 = acc[mt][2][r] * arf[2] + acc[mt][3][r] * arf[3];
      #pragma unroll
      for (int o = 1; o < 16; o <<= 1) {
        sl0 += __shfl_xor(sl0, o);
        sl1 += __shfl_xor(sl1, o);
        sr0 += __shfl_xor(sr0, o);
        sr1 += __shfl_xor(sr1, o);
      }
      int row = rowBase + wm + mt * 16 + quad * 4 + r;
      if (l16 == 0 && row < N_NODES) {
        *(float2*)&el[row * 4 + h0] = make_float2(sl0, sl1);
        *(float2*)&er[row * 4 + h0] = make_float2(sr0, sr1);
      }
    }
  }
}

// ---------------- phase 1: bucket edges by dst>>8, packed (src<<8)|dlocal ---
__global__ __launch_bounds__(256) void k_bucket(const int* __restrict__ src,
                                                const int* __restrict__ dst,
                                                int* __restrict__ gfill,
                                                unsigned* __restrict__ pairs,
                                                int* __restrict__ offs) {
  __shared__ int bcnt[NB];
  __shared__ int brsv[NB];
  __shared__ int brank[NB];
  int t = threadIdx.x;
  if (blockIdx.x == 0 && t == 0) offs[N_NODES] = N_EDGES;
  for (int tile = blockIdx.x; tile < N_TILES; tile += gridDim.x) {
    int e0 = tile * TILE + t * EPT;
    for (int i = t; i < NB; i += 256) { bcnt[i] = 0; brank[i] = 0; }
    __syncthreads();
    int ds[EPT], ss[EPT];
    if (e0 + EPT <= N_EDGES) {
      *(int4*)&ds[0] = *(const int4*)&dst[e0];
      *(int4*)&ds[4] = *(const int4*)&dst[e0 + 4];
      *(int4*)&ss[0] = *(const int4*)&src[e0];
      *(int4*)&ss[4] = *(const int4*)&src[e0 + 4];
    } else {
      #pragma unroll
      for (int k = 0; k < EPT; ++k) {
        int e = e0 + k;
        ds[k] = (e < N_EDGES) ? dst[e] : -1;
        ss[k] = (e < N_EDGES) ? src[e] : 0;
      }
    }
    #pragma unroll
    for (int k = 0; k < EPT; ++k)
      if (ds[k] >= 0) atomicAdd(&bcnt[ds[k] >> BUCKET_SHIFT], 1);
    __syncthreads();
    for (int i = t; i < NB; i += 256) {
      int c = bcnt[i];
      brsv[i] = (c > 0) ? atomicAdd(&gfill[i], c) : 0;
    }
    __syncthreads();
    #pragma unroll
    for (int k = 0; k < EPT; ++k) {
      if (ds[k] >= 0) {
        int b = ds[k] >> BUCKET_SHIFT;
        int r = brsv[b] + atomicAdd(&brank[b], 1);
        if (r < CAP)
          pairs[(size_t)b * CAP + r] =
              ((unsigned)ss[k] << 8) | (unsigned)(ds[k] & (BUCKET_NODES - 1));
      }
    }
    __syncthreads();
  }
}

// ---------------- phase 2: per-bucket counting sort -> offs, ssrc -----------
// bbase computed inline: each block reduces gfill[0..b-1] itself.
__global__ __launch_bounds__(512) void k_localsort(const unsigned* __restrict__ pairs,
                                                   const int* __restrict__ gfill,
                                                   int* __restrict__ offs,
                                                   int* __restrict__ ssrc) {
  __shared__ int cnt_l[256];
  __shared__ int ss[256];
  __shared__ int cur_l[256];
  __shared__ int redsum[8];
  __shared__ int s_base;
  int b = blockIdx.x, t = threadIdx.x;
  // inline prefix: base = sum_{i<b} gfill[i]
  {
    int v = (t < NB && t < b) ? gfill[t] : 0;
    #pragma unroll
    for (int o = 32; o > 0; o >>= 1) v += __shfl_xor(v, o);
    if ((t & 63) == 0) redsum[t >> 6] = v;
  }
  if (t < 256) cnt_l[t] = 0;
  __syncthreads();
  if (t == 0) {
    int s = 0;
    #pragma unroll
    for (int i = 0; i < 8; ++i) s += redsum[i];
    s_base = s;
  }
  int E = min(gfill[b], CAP);
  const unsigned* pb = &pairs[(size_t)b * CAP];
  __syncthreads();
  int base = s_base;
  for (int i = t; i < E; i += 512)
    atomicAdd(&cnt_l[pb[i] & (BUCKET_NODES - 1)], 1);
  __syncthreads();
  if (t < 256) ss[t] = cnt_l[t];
  __syncthreads();
  #pragma unroll
  for (int d = 1; d < 256; d <<= 1) {
    int u = (t < 256 && t >= d) ? ss[t - d] : 0;
    __syncthreads();
    if (t < 256) ss[t] += u;
    __syncthreads();
  }
  if (t < 256) {
    int pre = (t == 0) ? 0 : ss[t - 1];
    int node = b * BUCKET_NODES + t;
    if (node < N_NODES) offs[node] = base + pre;
    cur_l[t] = pre;
  }
  __syncthreads();
  for (int i = t; i < E; i += 512) {
    unsigned p = pb[i];
    int pos = atomicAdd(&cur_l[p & (BUCKET_NODES - 1)], 1);
    ssrc[base + pos] = (int)(p >> 8);
  }
}

// ---------------- per-node softmax + weighted aggregation (bf16 ft) --------
// Half-wave (32 lanes) per node: softmax in one chunk for deg<=32
// (Poisson(16): P(deg>32) ~ 1e-4), chunked fallback otherwise.
#define AH_PAD 36
__global__ __launch_bounds__(256) void k_agg(const int* __restrict__ offs,
                                             const int* __restrict__ ssrc,
                                             const unsigned short* __restrict__ ftb,
                                             const float* __restrict__ el,
                                             const float* __restrict__ er,
                                             float* __restrict__ out) {
  __shared__ int   lds_s[4][2][32];
  __shared__ float lds_ah[4][2][4][AH_PAD];
  int wave = threadIdx.x >> 6;
  int lane = threadIdx.x & 63;
  int half = lane >> 5;
  int l32 = lane & 31;
  int n = blockIdx.x * 8 + wave * 2 + half;
  if (n >= N_NODES) return;
  int start = offs[n], end = offs[n + 1];
  int deg = end - start;

  int* sS = lds_s[wave][half];
  float (*sA)[AH_PAD] = lds_ah[wave][half];

  // aggregation lane roles: 4 cols per lane
  int c4 = l32 * 4;
  int hh = l32 >> 3;
  const unsigned short* fb = ftb + c4;
  float a0 = 0.f, a1 = 0.f, a2 = 0.f, a3 = 0.f;

  float4 er4 = *(const float4*)&er[n * 4];

  if (deg <= 32) {
    bool valid = l32 < deg;
    int s = valid ? ssrc[start + l32] : 0;
    float4 e4 = *(const float4*)&el[s * 4];
    float v[4] = {e4.x + er4.x, e4.y + er4.y, e4.z + er4.z, e4.w + er4.w};
    float m[4], ex[4], den[4];
    #pragma unroll
    for (int h = 0; h < 4; ++h) {
      v[h] = v[h] > 0.f ? v[h] : NEG_SLOPE * v[h];
      m[h] = valid ? v[h] : -INFINITY;
    }
    #pragma unroll
    for (int h = 0; h < 4; ++h)
      #pragma unroll
      for (int o = 16; o > 0; o >>= 1) m[h] = fmaxf(m[h], __shfl_xor(m[h], o));
    #pragma unroll
    for (int h = 0; h < 4; ++h) {
      ex[h] = valid ? __expf(v[h] - m[h]) : 0.f;
      den[h] = ex[h];
    }
    #pragma unroll
    for (int h = 0; h < 4; ++h)
      #pragma unroll
      for (int o = 16; o > 0; o >>= 1) den[h] += __shfl_xor(den[h], o);
    sS[l32] = s;
    #pragma unroll
    for (int h = 0; h < 4; ++h) sA[h][l32] = ex[h] / den[h];  // deg==0: NaN, never read
    __builtin_amdgcn_wave_barrier();
    for (int j = 0; j < deg; j += 4) {
      int4   sv = *(const int4*)&sS[j];
      float4 av = *(const float4*)&sA[hh][j];
      uint2 uA = *(const uint2*)&fb[(size_t)sv.x * D_HID];
      uint2 uB = *(const uint2*)&fb[(size_t)sv.y * D_HID];
      uint2 uC = *(const uint2*)&fb[(size_t)sv.z * D_HID];
      uint2 uD = *(const uint2*)&fb[(size_t)sv.w * D_HID];
      a0 += av.x * bfu_lo(uA.x); a1 += av.x * bfu_hi(uA.x);
      a2 += av.x * bfu_lo(uA.y); a3 += av.x * bfu_hi(uA.y);
      a0 += av.y * bfu_lo(uB.x); a1 += av.y * bfu_hi(uB.x);
      a2 += av.y * bfu_lo(uB.y); a3 += av.y * bfu_hi(uB.y);
      a0 += av.z * bfu_lo(uC.x); a1 += av.z * bfu_hi(uC.x);
      a2 += av.z * bfu_lo(uC.y); a3 += av.z * bfu_hi(uC.y);
      a0 += av.w * bfu_lo(uD.x); a1 += av.w * bfu_hi(uD.x);
      a2 += av.w * bfu_lo(uD.y); a3 += av.w * bfu_hi(uD.y);
    }
  } else {
    // ---- rare chunked path (deg > 32) ----
    float erh[4] = {er4.x, er4.y, er4.z, er4.w};
    float m[4] = {-INFINITY, -INFINITY, -INFINITY, -INFINITY};
    for (int c = start; c < end; c += 32) {
      int i = c + l32;
      bool valid = i < end;
      int s = valid ? ssrc[i] : 0;
      float4 e4 = *(const float4*)&el[s * 4];
      float ee[4] = {e4.x, e4.y, e4.z, e4.w};
      #pragma unroll
      for (int h = 0; h < 4; ++h) {
        float v = ee[h] + erh[h];
        v = v > 0.f ? v : NEG_SLOPE * v;
        m[h] = fmaxf(m[h], valid ? v : -INFINITY);
      }
    }
    #pragma unroll
    for (int h = 0; h < 4; ++h)
      #pragma unroll
      for (int o = 16; o > 0; o >>= 1) m[h] = fmaxf(m[h], __shfl_xor(m[h], o));
    float den[4] = {0.f, 0.f, 0.f, 0.f};
    for (int c = start; c < end; c += 32) {
      int i = c + l32;
      bool valid = i < end;
      int s = valid ? ssrc[i] : 0;
      float4 e4 = *(const float4*)&el[s * 4];
      float ee[4] = {e4.x, e4.y, e4.z, e4.w};
      #pragma unroll
      for (int h = 0; h < 4; ++h) {
        float v = ee[h] + erh[h];
        v = v > 0.f ? v : NEG_SLOPE * v;
        den[h] += valid ? __expf(v - m[h]) : 0.f;
      }
    }
    #pragma unroll
    for (int h = 0; h < 4; ++h)
      #pragma unroll
      for (int o = 16; o > 0; o >>= 1) den[h] += __shfl_xor(den[h], o);
    float invd[4];
    #pragma unroll
    for (int h = 0; h < 4; ++h) invd[h] = 1.f / den[h];
    for (int c = start; c < end; c += 32) {
      int i = c + l32;
      bool valid = i < end;
      int s = valid ? ssrc[i] : 0;
      float4 e4 = *(const float4*)&el[s * 4];
      float ee[4] = {e4.x, e4.y, e4.z, e4.w};
      float av[4];
      #pragma unroll
      for (int h = 0; h < 4; ++h) {
        float v = ee[h] + erh[h];
        v = v > 0.f ? v : NEG_SLOPE * v;
        av[h] = valid ? __expf(v - m[h]) * invd[h] : 0.f;
      }
      __builtin_amdgcn_wave_barrier();   // previous chunk's reads done
      sS[l32] = s;
      #pragma unroll
      for (int h = 0; h < 4; ++h) sA[h][l32] = av[h];
      __builtin_amdgcn_wave_barrier();
      int cnt = min(32, end - c);
      for (int j = 0; j < cnt; j += 4) {
        int4   sv = *(const int4*)&sS[j];
        float4 aw = *(const float4*)&sA[hh][j];
        uint2 uA = *(const uint2*)&fb[(size_t)sv.x * D_HID];
        uint2 uB = *(const uint2*)&fb[(size_t)sv.y * D_HID];
        uint2 uC = *(const uint2*)&fb[(size_t)sv.z * D_HID];
        uint2 uD = *(const uint2*)&fb[(size_t)sv.w * D_HID];
        a0 += aw.x * bfu_lo(uA.x); a1 += aw.x * bfu_hi(uA.x);
        a2 += aw.x * bfu_lo(uA.y); a3 += aw.x * bfu_hi(uA.y);
        a0 += aw.y * bfu_lo(uB.x); a1 += aw.y * bfu_hi(uB.x);
        a2 += aw.y * bfu_lo(uB.y); a3 += aw.y * bfu_hi(uB.y);
        a0 += aw.z * bfu_lo(uC.x); a1 += aw.z * bfu_hi(uC.x);
        a2 += aw.z * bfu_lo(uC.y); a3 += aw.z * bfu_hi(uC.y);
        a0 += aw.w * bfu_lo(uD.x); a1 += aw.w * bfu_hi(uD.x);
        a2 += aw.w * bfu_lo(uD.y); a3 += aw.w * bfu_hi(uD.y);
      }
    }
  }
  *(float4*)&out[(size_t)n * D_HID + c4] = make_float4(a0, a1, a2, a3);
}

extern "C" void kernel_launch(void* const* d_in, const int* in_sizes, int n_in,
                              void* d_out, int out_size, void* d_ws, size_t ws_size,
                              hipStream_t stream) {
  const float* x      = (const float*)d_in[0];
  const float* fc_w   = (const float*)d_in[1];
  const float* attn_l = (const float*)d_in[2];
  const float* attn_r = (const float*)d_in[3];
  const int*   src    = (const int*)d_in[4];
  const int*   dst    = (const int*)d_in[5];
  float* out = (float*)d_out;

  char* wsp = (char*)d_ws;
  size_t off = 0;
  auto alloc = [&](size_t bytes) {
    void* p = wsp + off;
    off = (off + bytes + 255) & ~(size_t)255;
    return p;
  };
  unsigned short* ftb = (unsigned short*)alloc((size_t)N_NODES * D_HID * 2);
  float* el     = (float*)alloc((size_t)N_NODES * 4 * 4);
  float* er     = (float*)alloc((size_t)N_NODES * 4 * 4);
  int*   offs   = (int*)alloc((size_t)(N_NODES + 1) * 4);
  int*   ssrc   = (int*)alloc((size_t)N_EDGES * 4);
  int*   gfill  = (int*)alloc((size_t)NB * 4);
  unsigned* pairs = (unsigned*)alloc((size_t)NB * CAP * 4);

  hipMemsetAsync(gfill, 0, (size_t)NB * 4, stream);
  k_gemm<<<(N_NODES + 127) / 128, 256, 0, stream>>>(x, fc_w, attn_l, attn_r, ftb, el, er);
  k_bucket<<<N_TILES, 256, 0, stream>>>(src, dst, gfill, pairs, offs);
  k_localsort<<<NB, 512, 0, stream>>>(pairs, gfill, offs, ssrc);
  k_agg<<<(N_NODES + 7) / 8, 256, 0, stream>>>(offs, ssrc, ftb, el, er, out);
}